// Round 1
// baseline (302.360 us; speedup 1.0000x reference)
//
#include <hip/hip_runtime.h>
#include <hip/hip_cooperative_groups.h>

namespace cg = cooperative_groups;

#define NB 128
#define NA 2
#define NH 128
#define NW 128
#define PLANE (NH * NW)            // 16384 floats per channel plane
#define RTHRESH 0.6f
#define OBJ_SCALE 5.0f

#define GRID  1024                 // 4 blocks/CU -> co-resident (16 waves/CU @ <=128 VGPR)
#define TPB   256
#define SWEEP (GRID * TPB)                  // 262,144 float4-granules per sweep
#define GRAN  (NB * NA * NH * NW / 4)       // 1,048,576 granules total
#define KSW   (GRAN / SWEEP)                // 4 sweeps per thread (16 cells)

__device__ __forceinline__ float sigm(float v) {
    return 1.0f / (1.0f + __expf(-v));
}

// Per-batch GT-box constants + best-anchor selection (tiny inputs, L1-hit,
// wave-uniform b -> scalar loads).
__device__ __forceinline__ void batch_const(const float* __restrict__ target,
                                            const float* __restrict__ anchors,
                                            int b,
                                            float& gx, float& gy, float& gw, float& gh,
                                            int& bn, int& gxi, int& gyi) {
    float t0 = target[b * 4 + 0], t1 = target[b * 4 + 1];
    float t2 = target[b * 4 + 2], t3 = target[b * 4 + 3];
    gx = t0 * (float)NW;
    gy = t1 * (float)NH;
    gw = t2 * (float)NW;
    gh = t3 * (float)NH;
    float a0w = anchors[0], a0h = anchors[1];
    float a1w = anchors[2], a1h = anchors[3];
    float i0 = fminf(gw, a0w) * fminf(gh, a0h);
    float u0 = gw * gh + 1e-16f + a0w * a0h - i0;
    float i1 = fminf(gw, a1w) * fminf(gh, a1h);
    float u1 = gw * gh + 1e-16f + a1w * a1h - i1;
    bn  = (i1 / u1 > i0 / u0) ? 1 : 0;   // argmax picks FIRST max
    gxi = (int)gx;   // gt_x in (12.8, 115.2): trunc == floor, in-bounds
    gyi = (int)gy;
}

// Final reduction + 128 selected-cell losses. Runs with TPB threads
// (block 0 of the fused kernel, or a standalone 1-block fallback kernel).
__device__ __forceinline__ void finale(const float* __restrict__ out,
                                       const float* __restrict__ target,
                                       const float* __restrict__ anchors,
                                       const float* __restrict__ psum,
                                       const unsigned int* __restrict__ pcnt,
                                       float* __restrict__ loss_out,
                                       int tid) {
    // Issue the scattered per-batch loads FIRST so they overlap the
    // partial-sum sweep below.
    float v = 0.0f;
    if (tid < NB) {
        int b = tid;
        float gx, gy, gw, gh; int bn, gxi, gyi;
        batch_const(target, anchors, b, gx, gy, gw, gh, bn, gxi, gyi);
        size_t base = (size_t)(b * 10 + bn * 5) * PLANE + (size_t)gyi * NW + (size_t)gxi;
        float xs = out[base];
        float ys = out[base + 1 * PLANE];
        float wr = out[base + 2 * PLANE];
        float hr = out[base + 3 * PLANE];
        float cs = out[base + 4 * PLANE];
        float tx = gx - floorf(gx);
        float ty = gy - floorf(gy);
        float aw = anchors[bn * 2 + 0];
        float ah = anchors[bn * 2 + 1];
        float tw = __logf(gw / aw + 1e-16f);
        float th = __logf(gh / ah + 1e-16f);
        float scale = 2.0f - target[b * 4 + 2] * target[b * 4 + 3];
        float dx = (sigm(xs) - tx) * scale;
        float dy = (sigm(ys) - ty) * scale;
        float dw = (wr - tw) * scale;
        float dh = (hr - th) * scale;
        float dc = sigm(cs) - 1.0f;
        v = dx * dx + dy * dy + dw * dw + dh * dh + OBJ_SCALE * dc * dc;
    }

    float s = 0.0f;
    unsigned int c = 0;
#pragma unroll
    for (int k = 0; k < GRID / TPB; ++k) {
        s += psum[tid + k * TPB];
        c += pcnt[tid + k * TPB];
    }

#pragma unroll
    for (int off = 32; off > 0; off >>= 1) {
        s += __shfl_down(s, off);
        c += __shfl_down(c, off);
        v += __shfl_down(v, off);
    }
    __shared__ float        fs[4];
    __shared__ unsigned int fc[4];
    __shared__ float        fv[4];
    int wid = tid >> 6, lane = tid & 63;
    if (lane == 0) { fs[wid] = s; fc[wid] = c; fv[wid] = v; }
    __syncthreads();
    if (tid == 0) {
        float ssum = fs[0] + fs[1] + fs[2] + fs[3];
        float csum = (float)(fc[0] + fc[1] + fc[2] + fc[3]);
        float vsum = fv[0] + fv[1] + fv[2] + fv[3];
        loss_out[0] = vsum * (1.0f / (float)NB) + ssum / csum;
    }
}

// Fused dense pass + grid.sync + block-0 finale.
// 1024 blocks x 256 threads x 16 cells = 4,194,304 cells. Per-block partial
// writes (NO same-address atomics: round-1 postmortem — 8192 same-line atomics
// serialized at ~30cy = ~85us; a 1024-wide atomic ticket would cost ~25us the
// same way, which is why grid.sync, not last-block-ticket, is used here).
__global__ __launch_bounds__(TPB, 4) void region_fused(
        const float* __restrict__ out,
        const float* __restrict__ target,
        const float* __restrict__ anchors,
        float* __restrict__ psum,
        unsigned int* __restrict__ pcnt,
        float* __restrict__ loss_out,
        int fused) {
    int tid = threadIdx.x;
    int tg  = blockIdx.x * TPB + tid;

    float lsum = 0.0f;
    int   lcnt = 0;

#pragma unroll
    for (int k = 0; k < KSW; ++k) {
        int g  = tg + k * SWEEP;            // each sweep fully coalesced
        int j0 = (g & 31) * 4;              // 4-aligned column
        int i  = (g >> 5) & 127;
        int a  = (g >> 12) & 1;
        int b  = g >> 13;                   // wave-uniform (64 | 8192)

        float gx, gy, gw, gh; int bn, gxi, gyi;
        batch_const(target, anchors, b, gx, gy, gw, gh, bn, gxi, gyi);
        float aw = anchors[a * 2 + 0];
        float ah = anchors[a * 2 + 1];

        size_t base = (size_t)(b * 10 + a * 5) * PLANE + (size_t)i * NW + (size_t)j0;
        float4 vx = *(const float4*)(out + base);
        float4 vy = *(const float4*)(out + base + 1 * PLANE);
        float4 vw = *(const float4*)(out + base + 2 * PLANE);
        float4 vh = *(const float4*)(out + base + 3 * PLANE);
        float4 vc = *(const float4*)(out + base + 4 * PLANE);

        float gxm = gx - gw * 0.5f, gxM = gx + gw * 0.5f;
        float gym = gy - gh * 0.5f, gyM = gy + gh * 0.5f;
        float garea = gw * gh;
        bool row_sel = (a == bn) && (i == gyi);

        const float* fx = (const float*)&vx;
        const float* fy = (const float*)&vy;
        const float* fw = (const float*)&vw;
        const float* fh = (const float*)&vh;
        const float* fc = (const float*)&vc;

#pragma unroll
        for (int e = 0; e < 4; ++e) {
            float px = sigm(fx[e]) + (float)(j0 + e);
            float py = sigm(fy[e]) + (float)i;
            float pw = __expf(fw[e]) * aw;
            float ph = __expf(fh[e]) * ah;
            float cf = sigm(fc[e]);

            float mx = fminf(px - pw * 0.5f, gxm);
            float Mx = fmaxf(px + pw * 0.5f, gxM);
            float my = fminf(py - ph * 0.5f, gym);
            float My = fmaxf(py + ph * 0.5f, gyM);
            float cw = pw + gw - (Mx - mx);
            float ch = ph + gh - (My - my);
            float iou = 0.0f;
            if (cw > 0.0f && ch > 0.0f) {
                float carea = cw * ch;
                iou = carea / (pw * ph + garea - carea);
            }
            bool noobj = (iou <= RTHRESH) && !(row_sel && (j0 + e) == gxi);
            if (noobj) { lsum += cf * cf; lcnt += 1; }
        }
    }

    // wave64 shuffle tree, then LDS across 4 waves, one store per block.
    // Every psum/pcnt slot written unconditionally -> poisoned ws is safe.
#pragma unroll
    for (int off = 32; off > 0; off >>= 1) {
        lsum += __shfl_down(lsum, off);
        lcnt += __shfl_down(lcnt, off);
    }
    __shared__ float ssum[4];
    __shared__ int   scnt[4];
    int wid = tid >> 6, lane = tid & 63;
    if (lane == 0) { ssum[wid] = lsum; scnt[wid] = lcnt; }
    __syncthreads();
    if (tid == 0) {
        psum[blockIdx.x] = ssum[0] + ssum[1] + ssum[2] + ssum[3];
        pcnt[blockIdx.x] = (unsigned int)(scnt[0] + scnt[1] + scnt[2] + scnt[3]);
    }

    if (!fused) return;                 // fallback path: separate final kernel

    __threadfence();                    // make partials device-visible (cross-XCD)
    cg::this_grid().sync();

    if (blockIdx.x != 0) return;
    finale(out, target, anchors, psum, pcnt, loss_out, tid);
}

// Fallback final kernel (used only if cooperative launch is rejected).
__global__ __launch_bounds__(TPB) void region_final2(
        const float* __restrict__ out,
        const float* __restrict__ target,
        const float* __restrict__ anchors,
        const float* __restrict__ psum,
        const unsigned int* __restrict__ pcnt,
        float* __restrict__ loss_out) {
    finale(out, target, anchors, psum, pcnt, loss_out, threadIdx.x);
}

extern "C" void kernel_launch(void* const* d_in, const int* in_sizes, int n_in,
                              void* d_out, int out_size, void* d_ws, size_t ws_size,
                              hipStream_t stream) {
    (void)in_sizes; (void)n_in; (void)out_size; (void)ws_size;
    const float* output  = (const float*)d_in[0];   // (128, 10, 128, 128) fp32
    const float* target  = (const float*)d_in[1];   // (128, 4)
    const float* anchors = (const float*)d_in[2];   // (2, 2)
    float* loss = (float*)d_out;

    // d_ws layout: [0,4K) float psum[1024]; [4K,8K) uint pcnt[1024].
    float* psum = (float*)d_ws;
    unsigned int* pcnt = (unsigned int*)((char*)d_ws + GRID * sizeof(float));

    int fused = 1;
    void* args[] = {(void*)&output, (void*)&target, (void*)&anchors,
                    (void*)&psum, (void*)&pcnt, (void*)&loss, (void*)&fused};
    hipError_t err = hipLaunchCooperativeKernel((const void*)region_fused,
                                                dim3(GRID), dim3(TPB),
                                                args, 0, stream);
    if (err != hipSuccess) {
        (void)hipGetLastError();        // clear sticky error, use 2-kernel path
        hipLaunchKernelGGL(region_fused, dim3(GRID), dim3(TPB), 0, stream,
                           output, target, anchors, psum, pcnt, loss, 0);
        hipLaunchKernelGGL(region_final2, dim3(1), dim3(TPB), 0, stream,
                           output, target, anchors, psum, pcnt, loss);
    }
}

// Round 2
// 121.695 us; speedup vs baseline: 2.4846x; 2.4846x over previous
//
#include <hip/hip_runtime.h>

#define NB 128
#define NA 2
#define NH 128
#define NW 128
#define PLANE (NH * NW)            // 16384 floats per channel plane
#define RTHRESH 0.6f
#define OBJ_SCALE 5.0f

#define GRID  2048                 // 8 blocks/CU resident (VGPR ~36)
#define TPB   256
#define SWEEP (GRID * TPB)                  // 524,288 float4-granules per sweep
#define GRAN  (NB * NA * NH * NW / 4)       // 1,048,576 granules total
#define KSW   (GRAN / SWEEP)                // 2 sweeps per thread (8 cells)

__device__ __forceinline__ float sigm(float v) {
    return 1.0f / (1.0f + __expf(-v));
}

// Per-batch GT-box constants + best-anchor selection (tiny inputs, L1-hit,
// wave-uniform b -> compiler emits scalar loads).
__device__ __forceinline__ void batch_const(const float* __restrict__ target,
                                            const float* __restrict__ anchors,
                                            int b,
                                            float& gx, float& gy, float& gw, float& gh,
                                            int& bn, int& gxi, int& gyi) {
    float t0 = target[b * 4 + 0], t1 = target[b * 4 + 1];
    float t2 = target[b * 4 + 2], t3 = target[b * 4 + 3];
    gx = t0 * (float)NW;
    gy = t1 * (float)NH;
    gw = t2 * (float)NW;
    gh = t3 * (float)NH;
    float a0w = anchors[0], a0h = anchors[1];
    float a1w = anchors[2], a1h = anchors[3];
    float i0 = fminf(gw, a0w) * fminf(gh, a0h);
    float u0 = gw * gh + 1e-16f + a0w * a0h - i0;
    float i1 = fminf(gw, a1w) * fminf(gh, a1h);
    float u1 = gw * gh + 1e-16f + a1w * a1h - i1;
    bn  = (i1 / u1 > i0 / u0) ? 1 : 0;   // argmax picks FIRST max
    gxi = (int)gx;   // gt_x in (12.8, 115.2): trunc == floor, in-bounds
    gyi = (int)gy;
}

// Dense pass. 2048 blocks x 256 threads x 8 cells = 4,194,304 cells.
// Thin threads (low VGPR -> 8 blocks/CU) + per-block partial writes.
// NO same-address atomics (round-1 postmortem: 8192 same-line atomics
// serialized ~85us) and NO grid.sync (round-2 postmortem: cooperative
// grid barrier on 1024 blocks cost ~170us of idle spin — 30x the dispatch
// it saved).
__global__ __launch_bounds__(TPB) void region_main(
        const float* __restrict__ out,
        const float* __restrict__ target,
        const float* __restrict__ anchors,
        float* __restrict__ psum,
        unsigned int* __restrict__ pcnt) {
    int tid = threadIdx.x;
    int tg  = blockIdx.x * TPB + tid;

    float lsum = 0.0f;
    int   lcnt = 0;

#pragma unroll
    for (int k = 0; k < KSW; ++k) {
        int g  = tg + k * SWEEP;            // each sweep fully coalesced
        int j0 = (g & 31) * 4;              // 4-aligned column
        int i  = (g >> 5) & 127;
        int a  = (g >> 12) & 1;
        int b  = g >> 13;                   // wave-uniform (64 | 8192)

        float gx, gy, gw, gh; int bn, gxi, gyi;
        batch_const(target, anchors, b, gx, gy, gw, gh, bn, gxi, gyi);
        float aw = anchors[a * 2 + 0];
        float ah = anchors[a * 2 + 1];

        size_t base = (size_t)(b * 10 + a * 5) * PLANE + (size_t)i * NW + (size_t)j0;
        float4 vx = *(const float4*)(out + base);
        float4 vy = *(const float4*)(out + base + 1 * PLANE);
        float4 vw = *(const float4*)(out + base + 2 * PLANE);
        float4 vh = *(const float4*)(out + base + 3 * PLANE);
        float4 vc = *(const float4*)(out + base + 4 * PLANE);

        float gxm = gx - gw * 0.5f, gxM = gx + gw * 0.5f;
        float gym = gy - gh * 0.5f, gyM = gy + gh * 0.5f;
        float garea = gw * gh;
        bool row_sel = (a == bn) && (i == gyi);

        const float* fx = (const float*)&vx;
        const float* fy = (const float*)&vy;
        const float* fw = (const float*)&vw;
        const float* fh = (const float*)&vh;
        const float* fc = (const float*)&vc;

#pragma unroll
        for (int e = 0; e < 4; ++e) {
            float px = sigm(fx[e]) + (float)(j0 + e);
            float py = sigm(fy[e]) + (float)i;
            float pw = __expf(fw[e]) * aw;
            float ph = __expf(fh[e]) * ah;
            float cf = sigm(fc[e]);

            float mx = fminf(px - pw * 0.5f, gxm);
            float Mx = fmaxf(px + pw * 0.5f, gxM);
            float my = fminf(py - ph * 0.5f, gym);
            float My = fmaxf(py + ph * 0.5f, gyM);
            float cw = pw + gw - (Mx - mx);
            float ch = ph + gh - (My - my);
            float iou = 0.0f;
            if (cw > 0.0f && ch > 0.0f) {
                float carea = cw * ch;
                iou = carea / (pw * ph + garea - carea);
            }
            bool noobj = (iou <= RTHRESH) && !(row_sel && (j0 + e) == gxi);
            if (noobj) { lsum += cf * cf; lcnt += 1; }
        }
    }

    // wave64 shuffle tree, then LDS across 4 waves, one store per block.
    // Every psum/pcnt slot written unconditionally -> poisoned ws is safe.
#pragma unroll
    for (int off = 32; off > 0; off >>= 1) {
        lsum += __shfl_down(lsum, off);
        lcnt += __shfl_down(lcnt, off);
    }
    __shared__ float ssum[4];
    __shared__ int   scnt[4];
    int wid = tid >> 6, lane = tid & 63;
    if (lane == 0) { ssum[wid] = lsum; scnt[wid] = lcnt; }
    __syncthreads();
    if (tid == 0) {
        psum[blockIdx.x] = ssum[0] + ssum[1] + ssum[2] + ssum[3];
        pcnt[blockIdx.x] = (unsigned int)(scnt[0] + scnt[1] + scnt[2] + scnt[3]);
    }
}

// Final: reduce 2048 partials + 128 selected-cell losses. 1 block, 1024 thr.
__global__ __launch_bounds__(1024) void region_final(
        const float* __restrict__ out,
        const float* __restrict__ target,
        const float* __restrict__ anchors,
        const float* __restrict__ psum,
        const unsigned int* __restrict__ pcnt,
        float* __restrict__ loss_out) {
    int t = threadIdx.x;

    // Issue the scattered per-batch loads FIRST so they overlap the
    // partial-sum sweep below.
    float v = 0.0f;
    if (t < NB) {
        int b = t;
        float gx, gy, gw, gh; int bn, gxi, gyi;
        batch_const(target, anchors, b, gx, gy, gw, gh, bn, gxi, gyi);
        size_t base = (size_t)(b * 10 + bn * 5) * PLANE + (size_t)gyi * NW + (size_t)gxi;
        float xs = out[base];
        float ys = out[base + 1 * PLANE];
        float wr = out[base + 2 * PLANE];
        float hr = out[base + 3 * PLANE];
        float cs = out[base + 4 * PLANE];
        float tx = gx - floorf(gx);
        float ty = gy - floorf(gy);
        float aw = anchors[bn * 2 + 0];
        float ah = anchors[bn * 2 + 1];
        float tw = __logf(gw / aw + 1e-16f);
        float th = __logf(gh / ah + 1e-16f);
        float scale = 2.0f - target[b * 4 + 2] * target[b * 4 + 3];
        float dx = (sigm(xs) - tx) * scale;
        float dy = (sigm(ys) - ty) * scale;
        float dw = (wr - tw) * scale;
        float dh = (hr - th) * scale;
        float dc = sigm(cs) - 1.0f;
        v = dx * dx + dy * dy + dw * dw + dh * dh + OBJ_SCALE * dc * dc;
    }

    float s = 0.0f;
    unsigned int c = 0;
#pragma unroll
    for (int k = 0; k < GRID / 1024; ++k) {
        s += psum[t + k * 1024];
        c += pcnt[t + k * 1024];
    }

#pragma unroll
    for (int off = 32; off > 0; off >>= 1) {
        s += __shfl_down(s, off);
        c += __shfl_down(c, off);
        v += __shfl_down(v, off);
    }
    __shared__ float ss[16];
    __shared__ unsigned int sc[16];
    __shared__ float sv[16];
    int wid = t >> 6, lane = t & 63;
    if (lane == 0) { ss[wid] = s; sc[wid] = c; sv[wid] = v; }
    __syncthreads();
    if (t < 16) {
        s = ss[t]; c = sc[t]; v = sv[t];
#pragma unroll
        for (int off = 8; off > 0; off >>= 1) {
            s += __shfl_down(s, off);
            c += __shfl_down(c, off);
            v += __shfl_down(v, off);
        }
        if (t == 0)
            loss_out[0] = v * (1.0f / (float)NB) + s / (float)c;
    }
}

extern "C" void kernel_launch(void* const* d_in, const int* in_sizes, int n_in,
                              void* d_out, int out_size, void* d_ws, size_t ws_size,
                              hipStream_t stream) {
    (void)in_sizes; (void)n_in; (void)out_size; (void)ws_size;
    const float* output  = (const float*)d_in[0];   // (128, 10, 128, 128) fp32
    const float* target  = (const float*)d_in[1];   // (128, 4)
    const float* anchors = (const float*)d_in[2];   // (2, 2)
    float* loss = (float*)d_out;

    // d_ws layout: [0,8K) float psum[2048]; [8K,16K) uint pcnt[2048].
    // Every slot written unconditionally -> no memset of poisoned ws needed.
    float* psum = (float*)d_ws;
    unsigned int* pcnt = (unsigned int*)((char*)d_ws + GRID * sizeof(float));

    region_main<<<GRID, TPB, 0, stream>>>(output, target, anchors, psum, pcnt);
    region_final<<<1, 1024, 0, stream>>>(output, target, anchors, psum, pcnt, loss);
}